// Round 7
// baseline (1713.078 us; speedup 1.0000x reference)
//
#include <hip/hip_runtime.h>

namespace {

constexpr int NN = 50000;   // nodes
constexpr int NE = 800000;  // edges
constexpr int NB = 64;      // graphs / batch
constexpr int NL = 32;      // path length
constexpr int ND = 256;     // D == H == 256
constexpr int NSCAN = 196;  // ceil(50176/256) scan blocks
constexpr int NPOOL = (NN + 63) / 64;  // 782 pool blocks

typedef __attribute__((ext_vector_type(8))) short short8v;  // 8 bf16 (4 VGPRs)
typedef __attribute__((ext_vector_type(4))) float float4v;  // MFMA accumulator

__device__ __forceinline__ float sigf(float x){ return 1.0f/(1.0f + __expf(-x)); }

__device__ __forceinline__ ushort rne_bf16(float f){
  uint u = __float_as_uint(f);
  return (ushort)((u + 0x7FFFu + ((u >> 16) & 1u)) >> 16);
}
__device__ __forceinline__ float bf2f(ushort u){ return __uint_as_float((uint)u << 16); }

// hi = RNE-bf16(f), lo = trunc-bf16(f - hi)
__device__ __forceinline__ void splitr(float f, ushort& h, ushort& lo){
  h = rne_bf16(f);
  float r = f - bf2f(h);
  lo = (ushort)(__float_as_uint(r) >> 16);
}

// split 8 fp32 -> 8 bf16-hi (truncated) + 8 bf16-lo (of remainder), packed 2/word
__device__ __forceinline__ void split8(float4 fa, float4 fb, uint4& h, uint4& lo){
  uint a0=__float_as_uint(fa.x), a1=__float_as_uint(fa.y), a2=__float_as_uint(fa.z), a3=__float_as_uint(fa.w);
  uint b0=__float_as_uint(fb.x), b1=__float_as_uint(fb.y), b2=__float_as_uint(fb.z), b3=__float_as_uint(fb.w);
  h.x = (a0>>16) | (a1 & 0xFFFF0000u);
  h.y = (a2>>16) | (a3 & 0xFFFF0000u);
  h.z = (b0>>16) | (b1 & 0xFFFF0000u);
  h.w = (b2>>16) | (b3 & 0xFFFF0000u);
  float r0 = fa.x - __uint_as_float(a0 & 0xFFFF0000u);
  float r1 = fa.y - __uint_as_float(a1 & 0xFFFF0000u);
  float r2 = fa.z - __uint_as_float(a2 & 0xFFFF0000u);
  float r3 = fa.w - __uint_as_float(a3 & 0xFFFF0000u);
  float r4 = fb.x - __uint_as_float(b0 & 0xFFFF0000u);
  float r5 = fb.y - __uint_as_float(b1 & 0xFFFF0000u);
  float r6 = fb.z - __uint_as_float(b2 & 0xFFFF0000u);
  float r7 = fb.w - __uint_as_float(b3 & 0xFFFF0000u);
  lo.x = (__float_as_uint(r0)>>16) | (__float_as_uint(r1) & 0xFFFF0000u);
  lo.y = (__float_as_uint(r2)>>16) | (__float_as_uint(r3) & 0xFFFF0000u);
  lo.z = (__float_as_uint(r4)>>16) | (__float_as_uint(r5) & 0xFFFF0000u);
  lo.w = (__float_as_uint(r6)>>16) | (__float_as_uint(r7) & 0xFFFF0000u);
}

// ================= CSR build (counting sort of edges by dst) =================
__global__ void k_hist(const int* __restrict__ dst, int* __restrict__ cnt){
  int stride = gridDim.x * blockDim.x;
  for (int e = blockIdx.x*blockDim.x + threadIdx.x; e < NE; e += stride)
    atomicAdd(&cnt[dst[e]], 1);
}

__global__ void k_scan_block(const int* __restrict__ cnt, int* __restrict__ offs,
                             int* __restrict__ bsum){
  __shared__ int s[256];
  const int t = threadIdx.x, i = blockIdx.x*256 + t;
  int v = cnt[i];
  s[t] = v; __syncthreads();
  #pragma unroll
  for (int off = 1; off < 256; off <<= 1){
    int x = (t >= off) ? s[t-off] : 0;
    __syncthreads();
    s[t] += x;
    __syncthreads();
  }
  offs[i] = s[t] - v;
  if (t == 255) bsum[blockIdx.x] = s[255];
}

__global__ void k_scan_top(const int* __restrict__ bsum, int* __restrict__ bsum2){
  __shared__ int s[256];
  const int t = threadIdx.x;
  int v = (t < NSCAN) ? bsum[t] : 0;
  s[t] = v; __syncthreads();
  #pragma unroll
  for (int off = 1; off < 256; off <<= 1){
    int x = (t >= off) ? s[t-off] : 0;
    __syncthreads();
    s[t] += x;
    __syncthreads();
  }
  if (t < NSCAN) bsum2[t] = s[t] - v;
}

__global__ void k_scan_add(int* __restrict__ offs, const int* __restrict__ bsum2,
                           int* __restrict__ cursor){
  const int i = blockIdx.x*256 + threadIdx.x;
  int v = offs[i] + bsum2[blockIdx.x];
  offs[i] = v;
  cursor[i] = v;
}

__global__ void k_fill(const int* __restrict__ src, const int* __restrict__ dst,
                       int* __restrict__ cursor, int* __restrict__ csr){
  int stride = gridDim.x * blockDim.x;
  for (int e = blockIdx.x*blockDim.x + threadIdx.x; e < NE; e += stride){
    int d = dst[e];
    int pos = atomicAdd(&cursor[d], 1);
    csr[pos] = src[e];
  }
}

// ================= fp32 -> bf16 (RNE) bulk convert =================
__global__ void k_tobf16(const float* __restrict__ in, ushort* __restrict__ out){
  const int i = blockIdx.x*blockDim.x + threadIdx.x;   // one per 8 elems
  const float4 a = ((const float4*)in)[i*2];
  const float4 b = ((const float4*)in)[i*2+1];
  ushort o[8] = { rne_bf16(a.x), rne_bf16(a.y), rne_bf16(a.z), rne_bf16(a.w),
                  rne_bf16(b.x), rne_bf16(b.y), rne_bf16(b.z), rne_bf16(b.w) };
  ((uint4*)out)[i] = *(uint4*)o;
}

// ================= mean-aggregate gather over bf16 features =================
// Output written pre-split RNE-hi / residual-lo.
__launch_bounds__(256, 8)
__global__ void k_gather_bf16(const ushort* __restrict__ feat, const int* __restrict__ offs,
                              const int* __restrict__ csr,
                              ushort* __restrict__ outH, ushort* __restrict__ outL){
  __shared__ float4 sp[256];
  const int u = blockIdx.x, t = threadIdx.x;
  const int w = t >> 6, l = t & 63;
  const int beg = offs[u], end = offs[u+1];
  const int lc = l * 4;
  float a0 = 0.f, a1 = 0.f, a2 = 0.f, a3 = 0.f;
  int e = beg + w;
  for (; e + 4 < end; e += 8){
    int s0 = csr[e], s1 = csr[e+4];
    ushort4 v0 = *(const ushort4*)(feat + (long long)s0*ND + lc);
    ushort4 v1 = *(const ushort4*)(feat + (long long)s1*ND + lc);
    a0 += bf2f(v0.x) + bf2f(v1.x);
    a1 += bf2f(v0.y) + bf2f(v1.y);
    a2 += bf2f(v0.z) + bf2f(v1.z);
    a3 += bf2f(v0.w) + bf2f(v1.w);
  }
  if (e < end){
    int s0 = csr[e];
    ushort4 v0 = *(const ushort4*)(feat + (long long)s0*ND + lc);
    a0 += bf2f(v0.x); a1 += bf2f(v0.y); a2 += bf2f(v0.z); a3 += bf2f(v0.w);
  }
  sp[t] = make_float4(a0, a1, a2, a3);
  __syncthreads();
  if (t < 64){
    float4 p0 = sp[t], p1 = sp[64+t], p2 = sp[128+t], p3 = sp[192+t];
    float inv = 1.0f / fmaxf((float)(end - beg), 1.0f);
    float4 r;
    r.x = (p0.x + p1.x + p2.x + p3.x) * inv;
    r.y = (p0.y + p1.y + p2.y + p3.y) * inv;
    r.z = (p0.z + p1.z + p2.z + p3.z) * inv;
    r.w = (p0.w + p1.w + p2.w + p3.w) * inv;
    ushort hh[4], ll[4];
    splitr(r.x, hh[0], ll[0]);
    splitr(r.y, hh[1], ll[1]);
    splitr(r.z, hh[2], ll[2]);
    splitr(r.w, hh[3], ll[3]);
    *(ushort4*)(outH + (long long)u*ND + t*4) = *(ushort4*)hh;
    *(ushort4*)(outL + (long long)u*ND + t*4) = *(ushort4*)ll;
  }
}

// ============ weight prep: fragment-linear swizzled [wl; wr] bf16 hi/lo ============
__global__ void k_wsplit(const float* __restrict__ wl, const float* __restrict__ wr,
                         ushort* __restrict__ WtH, ushort* __restrict__ WtL){
  const int k = blockIdx.x;    // 0..511
  const int n = threadIdx.x;   // 0..255
  float v = (k < 256) ? wl[k*256 + n] : wr[(k-256)*256 + n];
  uint u = __float_as_uint(v);
  float r = v - __uint_as_float(u & 0xFFFF0000u);
  const int wc = n >> 6, nt = (n >> 4) & 3, lm = n & 15;
  const int kk = k >> 5, lq = (k >> 3) & 3, j = k & 7;
  const long long idx = (long long)(((wc*4 + nt)*16 + kk)*64 + lq*16 + lm)*8 + j;
  WtH[idx] = (ushort)(u >> 16);
  WtL[idx] = (ushort)(__float_as_uint(r) >> 16);
}

// ============ unified MFMA SAGE GEMM: 64x256 tile, 1-D grid, pinned deep prefetch ============
template<int A2F32, int RELU>
__launch_bounds__(256, 2)
__global__ void k_gemm(const ushort* A1H, const ushort* A1L,
                       const ushort* A2H, const ushort* A2L,
                       const float*  A2F,
                       const ushort* __restrict__ WtH, const ushort* __restrict__ WtL,
                       const float* __restrict__ bias,
                       ushort* CH, ushort* CL)
{
  __shared__ float eb[16*260];          // 16.6 KB epilogue staging
  const int t  = threadIdx.x;
  const int w  = t >> 6;                // wave 0..3
  const int l  = t & 63;                // lane
  const int lm = l & 15;
  const int lq = l >> 4;
  const int m0 = blockIdx.x * 64;

  const uint4* BH4 = (const uint4*)WtH;
  const uint4* BL4 = (const uint4*)WtL;

  const float4v vzero = {0.f, 0.f, 0.f, 0.f};
  float4v acc[4][4];
  #pragma unroll
  for (int i = 0; i < 4; ++i)
    #pragma unroll
    for (int j = 0; j < 4; ++j) acc[i][j] = vzero;

  long long arow[4];
  #pragma unroll
  for (int mt = 0; mt < 4; ++mt){
    int row = m0 + mt*16 + lm;
    row = (row < NN) ? row : (NN - 1);  // clamp in-tile; dup rows discarded by store guard
    arow[mt] = (long long)row * ND;
  }
  int bbase[4];
  #pragma unroll
  for (int nt = 0; nt < 4; ++nt) bbase[nt] = (w*4 + nt)*1024 + l;

  uint4 aP[3][4], aQ[3][4];
  uint4 bh[2][4], bl[2][4];

  auto ldB = [&](int kk, int s){
    #pragma unroll
    for (int nt = 0; nt < 4; ++nt){
      const int idx = bbase[nt] + kk*64;
      bh[s][nt] = BH4[idx];
      bl[s][nt] = BL4[idx];
    }
  };
  auto ldA = [&](int kk, int s){
    const int koff = (kk & 7)*32 + lq*8;
    if (kk < 8 || !A2F32){
      const ushort* Hb = (kk < 8) ? A1H : A2H;
      const ushort* Lb = (kk < 8) ? A1L : A2L;
      #pragma unroll
      for (int mt = 0; mt < 4; ++mt){
        aP[s][mt] = *(const uint4*)(Hb + arow[mt] + koff);
        aQ[s][mt] = *(const uint4*)(Lb + arow[mt] + koff);
      }
    } else {
      #pragma unroll
      for (int mt = 0; mt < 4; ++mt){
        const float* p = A2F + arow[mt] + koff;
        aP[s][mt] = *(const uint4*)p;        // fa bits
        aQ[s][mt] = *(const uint4*)(p + 4);  // fb bits
      }
    }
  };

  ldA(0, 0);
  ldB(0, 0);
  ldA(1, 1);

  #pragma unroll
  for (int kk = 0; kk < 16; ++kk){
    const int c3 = kk % 3;
    const int cB = kk & 1;
    if (kk < 15) ldB(kk + 1, cB ^ 1);
    if (kk < 14) ldA(kk + 2, (kk + 2) % 3);
    __builtin_amdgcn_sched_barrier(0);   // pin: loads above may not sink past here

    uint4 ah[4], al[4];
    if (kk < 8 || !A2F32){
      #pragma unroll
      for (int mt = 0; mt < 4; ++mt){ ah[mt] = aP[c3][mt]; al[mt] = aQ[c3][mt]; }
    } else {
      #pragma unroll
      for (int mt = 0; mt < 4; ++mt){
        float4 fa = *(float4*)&aP[c3][mt];
        float4 fb = *(float4*)&aQ[c3][mt];
        split8(fa, fb, ah[mt], al[mt]);
      }
    }

    #pragma unroll
    for (int nt = 0; nt < 4; ++nt){
      short8v bhv = *(short8v*)&bh[cB][nt];
      short8v blv = *(short8v*)&bl[cB][nt];
      #pragma unroll
      for (int mt = 0; mt < 4; ++mt){
        short8v ahv = *(short8v*)&ah[mt];
        short8v alv = *(short8v*)&al[mt];
        acc[mt][nt] = __builtin_amdgcn_mfma_f32_16x16x32_bf16(ahv, bhv, acc[mt][nt], 0, 0, 0);
        acc[mt][nt] = __builtin_amdgcn_mfma_f32_16x16x32_bf16(alv, bhv, acc[mt][nt], 0, 0, 0);
        acc[mt][nt] = __builtin_amdgcn_mfma_f32_16x16x32_bf16(ahv, blv, acc[mt][nt], 0, 0, 0);
      }
    }
  }

  // ---- epilogue: LDS transpose per 16-row slab, coalesced RNE-hi/lo stores ----
  float bvv[4];
  #pragma unroll
  for (int nt = 0; nt < 4; ++nt) bvv[nt] = bias[w*64 + nt*16 + lm];

  #pragma unroll
  for (int mt = 0; mt < 4; ++mt){
    #pragma unroll
    for (int nt = 0; nt < 4; ++nt){
      #pragma unroll
      for (int r = 0; r < 4; ++r){
        float v = acc[mt][nt][r] + bvv[nt];
        if (RELU) v = fmaxf(v, 0.f);
        eb[(lq*4 + r)*260 + w*64 + nt*16 + lm] = v;   // C/D: col=lane&15, row=quad*4+reg
      }
    }
    __syncthreads();
    #pragma unroll
    for (int i = 0; i < 4; ++i){
      int idx = i*256 + t;           // 0..1023
      int rr  = idx >> 6;            // 0..15
      int c4  = (idx & 63) * 4;      // 0..252
      int grow = m0 + mt*16 + rr;
      if (grow < NN){
        float4 fv = *(float4*)&eb[rr*260 + c4];
        ushort hh[4], ll[4];
        splitr(fv.x, hh[0], ll[0]);
        splitr(fv.y, hh[1], ll[1]);
        splitr(fv.z, hh[2], ll[2]);
        splitr(fv.w, hh[3], ll[3]);
        *(ushort4*)(CH + (long long)grow*ND + c4) = *(ushort4*)hh;
        *(ushort4*)(CL + (long long)grow*ND + c4) = *(ushort4*)ll;
      }
    }
    __syncthreads();
  }
}

// ---------------- LSTM input gates ----------------
__launch_bounds__(256, 3)
__global__ void k_xgate(const ushort* __restrict__ EH, const ushort* __restrict__ EL,
                        const int* __restrict__ paths,
                        const float* __restrict__ w_ih, const float* __restrict__ b_ih,
                        const float* __restrict__ b_hh, float* __restrict__ xg)
{
  __shared__ float As[16][68];
  __shared__ float Ws[16][260];
  const int t  = threadIdx.x;
  const int m0 = blockIdx.x * 64;    // path rows (2048 total)
  const int g0 = blockIdx.y * 256;   // gate cols (1024 total)
  const int rg = t >> 5, cg = t & 31;
  const int sm = t >> 2, sj = (t & 3) * 4;

  float acc[8][8];
  #pragma unroll
  for (int i = 0; i < 8; ++i)
    #pragma unroll
    for (int j = 0; j < 8; ++j) acc[i][j] = 0.f;

  const int node = paths[m0 + sm];
  const ushort* ehrow = EH + (long long)node*ND;
  const ushort* elrow = EL + (long long)node*ND;
  const float* wrow = w_ih + (long long)(g0 + t)*ND;

  for (int k0 = 0; k0 < 256; k0 += 16){
    ushort4 hv = *(const ushort4*)(ehrow + k0 + sj);
    ushort4 lv = *(const ushort4*)(elrow + k0 + sj);
    float av0 = bf2f(hv.x) + bf2f(lv.x);
    float av1 = bf2f(hv.y) + bf2f(lv.y);
    float av2 = bf2f(hv.z) + bf2f(lv.z);
    float av3 = bf2f(hv.w) + bf2f(lv.w);
    float4 q0 = *(const float4*)(wrow + k0 + 0);
    float4 q1 = *(const float4*)(wrow + k0 + 4);
    float4 q2 = *(const float4*)(wrow + k0 + 8);
    float4 q3 = *(const float4*)(wrow + k0 + 12);
    __syncthreads();
    As[sj+0][sm]=av0; As[sj+1][sm]=av1; As[sj+2][sm]=av2; As[sj+3][sm]=av3;
    Ws[ 0][t]=q0.x; Ws[ 1][t]=q0.y; Ws[ 2][t]=q0.z; Ws[ 3][t]=q0.w;
    Ws[ 4][t]=q1.x; Ws[ 5][t]=q1.y; Ws[ 6][t]=q1.z; Ws[ 7][t]=q1.w;
    Ws[ 8][t]=q2.x; Ws[ 9][t]=q2.y; Ws[10][t]=q2.z; Ws[11][t]=q2.w;
    Ws[12][t]=q3.x; Ws[13][t]=q3.y; Ws[14][t]=q3.z; Ws[15][t]=q3.w;
    __syncthreads();
    #pragma unroll
    for (int k = 0; k < 16; ++k){
      float a[8], b[8];
      *(float4*)&a[0] = *(const float4*)&As[k][rg*8];
      *(float4*)&a[4] = *(const float4*)&As[k][rg*8+4];
      *(float4*)&b[0] = *(const float4*)&Ws[k][cg*8];
      *(float4*)&b[4] = *(const float4*)&Ws[k][cg*8+4];
      #pragma unroll
      for (int i = 0; i < 8; ++i)
        #pragma unroll
        for (int j = 0; j < 8; ++j)
          acc[i][j] = fmaf(a[i], b[j], acc[i][j]);
    }
  }

  float bv[8];
  #pragma unroll
  for (int j = 0; j < 8; ++j){ int g = g0 + cg*8 + j; bv[j] = b_ih[g] + b_hh[g]; }
  #pragma unroll
  for (int i = 0; i < 8; ++i){
    int row = m0 + rg*8 + i;
    float o[8];
    #pragma unroll
    for (int j = 0; j < 8; ++j) o[j] = acc[i][j] + bv[j];
    *(float4*)(xg + (long long)row*1024 + g0 + cg*8 + 0) = *(float4*)&o[0];
    *(float4*)(xg + (long long)row*1024 + g0 + cg*8 + 4) = *(float4*)&o[4];
  }
}

// ---------------- fused LSTM: one block per BATCH (sequences are independent) ----------------
// 64 blocks x 1024 threads. Thread t owns w_hh row t (= gate*256 + unit); its 1 KB row
// pointer is fixed for the whole kernel (all k-loads use immediate offsets). h lives in
// LDS (wave-uniform broadcast reads); c[u] lives in a register of thread u (t<256).
// NO inter-block communication, NO barrier tricks, NO co-residency assumption.
// w_hh (1 MB) is re-read from L2 each step (all 64 blocks share it -> L2-hot).
// Summation order matches the previous 32-launch version exactly (two halves, then +xg).
__launch_bounds__(1024, 4)
__global__ void k_lstm_batch(const float* __restrict__ xg, const float* __restrict__ w_hh,
                             float* __restrict__ hfin)
{
  __shared__ float hcur[256];
  __shared__ float gs[1024];
  const int t = threadIdx.x;          // = gate*256 + unit
  const int b = blockIdx.x;           // batch element
  const float* wrow = w_hh + (long long)t * 256;
  float c_reg = 0.f;                  // thread t<256 owns c[unit=t]

  for (int ts = 0; ts < NL; ++ts){
    float s;
    if (ts == 0){
      s = 0.f;                        // h0 == 0 -> recurrent term vanishes
    } else {
      float s0 = 0.f, s1 = 0.f;
      #pragma unroll
      for (int k4 = 0; k4 < 32; ++k4){
        float4 h4 = *(const float4*)&hcur[k4*4];
        float4 w4 = *(const float4*)(wrow + k4*4);
        s0 += h4.x*w4.x + h4.y*w4.y + h4.z*w4.z + h4.w*w4.w;
      }
      #pragma unroll
      for (int k4 = 32; k4 < 64; ++k4){
        float4 h4 = *(const float4*)&hcur[k4*4];
        float4 w4 = *(const float4*)(wrow + k4*4);
        s1 += h4.x*w4.x + h4.y*w4.y + h4.z*w4.z + h4.w*w4.w;
      }
      s = s0 + s1;
    }
    s += xg[((long long)b*NL + ts)*1024 + t];
    gs[t] = s;
    __syncthreads();
    if (t < 256){
      float gi = gs[t], gf = gs[256+t], gG = gs[512+t], go = gs[768+t];
      float c_new = sigf(gf)*c_reg + sigf(gi)*tanhf(gG);
      c_reg = c_new;
      float h = sigf(go)*tanhf(c_new);
      hcur[t] = h;
      if (ts == NL-1) hfin[b*256 + t] = h;
    }
    __syncthreads();
  }
}

// ---------------- global mean pool (hi/lo bf16 input), chunk-parallel ----------------
__launch_bounds__(256, 8)
__global__ void k_pool(const ushort* __restrict__ EH, const ushort* __restrict__ EL,
                       const int* __restrict__ batch,
                       float* __restrict__ gsum, float* __restrict__ gcnt)
{
  __shared__ int bs[64];
  __shared__ int uni;
  __shared__ float spf[8*256];
  const int t  = threadIdx.x;
  const int m0 = blockIdx.x * 64;
  const int r  = t >> 5;        // row-lane 0..7
  const int c  = t & 31;        // colgroup 0..31 (8 elems each)
  if (t == 0) uni = 1;
  if (t < 64){
    int n = m0 + t;
    bs[t] = (n < NN) ? batch[n] : -1;
  }
  __syncthreads();
  if (t < 64 && bs[t] != bs[0]) uni = 0;
  __syncthreads();

  const ushort* eh = EH + (long long)m0*ND + c*8;
  const ushort* el = EL + (long long)m0*ND + c*8;

  if (uni){
    float a[8];
    #pragma unroll
    for (int j = 0; j < 8; ++j) a[j] = 0.f;
    #pragma unroll
    for (int i = 0; i < 8; ++i){
      const int row = r*8 + i;
      const uint4 hv = *(const uint4*)(eh + (long long)row*ND);
      const uint4 lv = *(const uint4*)(el + (long long)row*ND);
      const ushort* hp = (const ushort*)&hv;
      const ushort* lp = (const ushort*)&lv;
      #pragma unroll
      for (int j = 0; j < 8; ++j) a[j] += bf2f(hp[j]) + bf2f(lp[j]);
    }
    #pragma unroll
    for (int j = 0; j < 8; ++j) spf[r*256 + c*8 + j] = a[j];
    __syncthreads();
    float s = spf[t] + spf[256+t] + spf[512+t] + spf[768+t]
            + spf[1024+t] + spf[1280+t] + spf[1536+t] + spf[1792+t];
    const int g = bs[0];
    unsafeAtomicAdd(&gsum[g*256 + t], s);
    if (t == 0) unsafeAtomicAdd(&gcnt[g], 64.0f);
  } else {
    float a[8];
    #pragma unroll
    for (int j = 0; j < 8; ++j) a[j] = 0.f;
    int cur = -1, cnt = 0;
    #pragma unroll
    for (int i = 0; i < 8; ++i){
      const int row = r*8 + i;
      const int g = bs[row];
      if (g != cur){
        if (cur >= 0){
          #pragma unroll
          for (int j = 0; j < 8; ++j) unsafeAtomicAdd(&gsum[cur*256 + c*8 + j], a[j]);
          if (c == 0) unsafeAtomicAdd(&gcnt[cur], (float)cnt);
        }
        #pragma unroll
        for (int j = 0; j < 8; ++j) a[j] = 0.f;
        cnt = 0; cur = g;
      }
      if (g >= 0){
        const uint4 hv = *(const uint4*)(eh + (long long)row*ND);
        const uint4 lv = *(const uint4*)(el + (long long)row*ND);
        const ushort* hp = (const ushort*)&hv;
        const ushort* lp = (const ushort*)&lv;
        #pragma unroll
        for (int j = 0; j < 8; ++j) a[j] += bf2f(hp[j]) + bf2f(lp[j]);
        ++cnt;
      }
    }
    if (cur >= 0){
      #pragma unroll
      for (int j = 0; j < 8; ++j) unsafeAtomicAdd(&gsum[cur*256 + c*8 + j], a[j]);
      if (c == 0) unsafeAtomicAdd(&gcnt[cur], (float)cnt);
    }
  }
}

// ---------------- scorer MLP (pool-finalize + concat fused in) ----------------
__global__ void k_score(const float* __restrict__ gsum, const float* __restrict__ gcnt,
                        const float* __restrict__ hfin, const float* __restrict__ wm1,
                        const float* __restrict__ bm1, const float* __restrict__ wm2,
                        const float* __restrict__ bm2, float* __restrict__ out)
{
  __shared__ float cs[512];
  __shared__ float red[4];
  const int b = blockIdx.x, t = threadIdx.x;
  float inv = 1.0f / fmaxf(gcnt[b], 1.0f);
  cs[t]       = gsum[b*256 + t] * inv;
  cs[256 + t] = hfin[b*256 + t];
  __syncthreads();
  float v = 0.f;
  #pragma unroll 4
  for (int k = 0; k < 512; ++k) v = fmaf(cs[k], wm1[(long long)k*256 + t], v);
  v = fmaxf(v + bm1[t], 0.f) * wm2[t];
  #pragma unroll
  for (int off = 32; off > 0; off >>= 1) v += __shfl_down(v, off, 64);
  if ((t & 63) == 0) red[t >> 6] = v;
  __syncthreads();
  if (t == 0) out[b] = red[0] + red[1] + red[2] + red[3] + bm2[0];
}

} // namespace

extern "C" void kernel_launch(void* const* d_in, const int* in_sizes, int n_in,
                              void* d_out, int out_size, void* d_ws, size_t ws_size,
                              hipStream_t stream)
{
  const float* x     = (const float*)d_in[0];
  const int*   eidx  = (const int*)  d_in[1];
  const int*   batch = (const int*)  d_in[2];
  const int*   paths = (const int*)  d_in[3];
  const float* w1l   = (const float*)d_in[4];
  const float* b1l   = (const float*)d_in[5];
  const float* w1r   = (const float*)d_in[6];
  const float* w2l   = (const float*)d_in[7];
  const float* b2l   = (const float*)d_in[8];
  const float* w2r   = (const float*)d_in[9];
  const float* w_ih  = (const float*)d_in[10];
  const float* w_hh  = (const float*)d_in[11];
  const float* b_ih  = (const float*)d_in[12];
  const float* b_hh  = (const float*)d_in[13];
  const float* wm1   = (const float*)d_in[14];
  const float* bm1   = (const float*)d_in[15];
  const float* wm2   = (const float*)d_in[16];
  const float* bm2   = (const float*)d_in[17];

  const int* src = eidx;        // edge_index[0]
  const int* dst = eidx + NE;   // edge_index[1]

  // workspace layout (same footprint as the original session, ~138 MB)
  float* w    = (float*)d_ws;
  float* bufA = w;                         // region0: gather out hi/lo (2 x NN*ND ushort)
  float* bufB = bufA + (long long)NN*ND;   // region1: h1 hi/lo -> node_emb hi/lo (in-place)
  float* xg   = bufB + (long long)NN*ND;   // 2048*1024 floats
  float* gsum = xg   + 2048*1024;          // 64*256
  float* gcnt = gsum + NB*ND;              // 64
  float* h0   = gcnt + 64;                 // 64*256 (final hidden state)
  float* c0   = h0   + NB*ND;              // 64*256 (unused now; c lives in registers)
  float* h1   = c0   + NB*ND;              // 64*256 (unused now)
  ushort* wt1H = (ushort*)(h1 + NB*ND);    // 256*512 each (bf16, fragment-swizzled)
  ushort* wt1L = wt1H + 256*512;
  ushort* wt2H = wt1L + 256*512;
  ushort* wt2L = wt2H + 256*512;
  ushort* fb16 = wt2L + 256*512;           // N*256 bf16: x RNE copy (gather-1 input)

  ushort* A1H = (ushort*)bufA;             // gather mean, hi
  ushort* A1L = A1H + (long long)NN*ND;    // gather mean, lo
  ushort* h1H = (ushort*)bufB;             // h1 RNE-hi (layer1 out) -> node_emb hi (layer2, in-place)
  ushort* h1L = h1H + (long long)NN*ND;    // h1 residual-lo       -> node_emb lo

  // CSR scratch aliased into xg region (dead until k_xgate runs, after layer 2)
  int* cnt    = (int*)xg;        // 50432
  int* offs   = cnt    + 50432;  // 50432
  int* cursor = offs   + 50432;  // 50432
  int* bsum   = cursor + 50432;  // 256
  int* bsum2  = bsum   + 256;    // 256
  int* csr    = bsum2  + 256;    // 800000

  // ---- weight prep (fragment-swizzled bf16 hi/lo split) ----
  k_wsplit<<<512, 256, 0, stream>>>(w1l, w1r, wt1H, wt1L);
  k_wsplit<<<512, 256, 0, stream>>>(w2l, w2r, wt2H, wt2L);

  // ---- x -> bf16 RNE copy (gather-1 input) ----
  k_tobf16<<<(NN*ND/8 + 255)/256, 256, 0, stream>>>(x, fb16);

  // ---- build CSR (counting sort by dst), shared by both layers ----
  hipMemsetAsync(cnt, 0, 50432*sizeof(int), stream);
  k_hist<<<1024, 256, 0, stream>>>(dst, cnt);
  k_scan_block<<<NSCAN, 256, 0, stream>>>(cnt, offs, bsum);
  k_scan_top<<<1, 256, 0, stream>>>(bsum, bsum2);
  k_scan_add<<<NSCAN, 256, 0, stream>>>(offs, bsum2, cursor);
  k_fill<<<1024, 256, 0, stream>>>(src, dst, cursor, csr);

  // ---- layer 1: gather-mean (pre-split); GEMM A2 = x fp32 (alias-free), relu ----
  k_gather_bf16<<<NN, 256, 0, stream>>>(fb16, offs, csr, A1H, A1L);
  k_gemm<1,1><<<782, 256, 0, stream>>>(A1H, A1L, nullptr, nullptr, x,
                                       wt1H, wt1L, b1l, h1H, h1L);

  // ---- layer 2: gather over RNE(relu(h1)) = h1H; GEMM all-pre-split, in-place ----
  k_gather_bf16<<<NN, 256, 0, stream>>>(h1H, offs, csr, A1H, A1L);
  k_gemm<0,0><<<782, 256, 0, stream>>>(A1H, A1L, h1H, h1L, nullptr,
                                       wt2H, wt2L, b2l, h1H, h1L);

  // ---- global mean pool (chunk-parallel, vectorized) ----
  hipMemsetAsync(gsum, 0, (NB*ND + 64)*sizeof(float), stream);
  k_pool<<<NPOOL, 256, 0, stream>>>(h1H, h1L, batch, gsum, gcnt);

  // ---- LSTM input gates (overwrites the CSR alias region — CSR dead by now) ----
  k_xgate<<<dim3((NB*NL)/64, 1024/256), 256, 0, stream>>>(h1H, h1L, paths, w_ih, b_ih, b_hh, xg);

  // ---- LSTM recurrence: ONE launch, one block per independent batch sequence ----
  k_lstm_batch<<<NB, 1024, 0, stream>>>(xg, w_hh, h0);
  // h0 = final hidden state

  // ---- fused concat + scorer ----
  k_score<<<NB, 256, 0, stream>>>(gsum, gcnt, h0, wm1, bm1, wm2, bm2, (float*)d_out);
}

// Round 8
// 967.840 us; speedup vs baseline: 1.7700x; 1.7700x over previous
//
#include <hip/hip_runtime.h>

namespace {

constexpr int NN = 50000;   // nodes
constexpr int NE = 800000;  // edges
constexpr int NB = 64;      // graphs / batch
constexpr int NL = 32;      // path length
constexpr int ND = 256;     // D == H == 256
constexpr int NSCAN = 196;  // ceil(50176/256) scan blocks
constexpr int NPOOL = (NN + 63) / 64;  // 782 pool blocks

typedef __attribute__((ext_vector_type(8))) short short8v;  // 8 bf16 (4 VGPRs)
typedef __attribute__((ext_vector_type(4))) float float4v;  // MFMA accumulator

__device__ __forceinline__ float sigf(float x){ return 1.0f/(1.0f + __expf(-x)); }

__device__ __forceinline__ ushort rne_bf16(float f){
  uint u = __float_as_uint(f);
  return (ushort)((u + 0x7FFFu + ((u >> 16) & 1u)) >> 16);
}
__device__ __forceinline__ float bf2f(ushort u){ return __uint_as_float((uint)u << 16); }

// hi = RNE-bf16(f), lo = trunc-bf16(f - hi)
__device__ __forceinline__ void splitr(float f, ushort& h, ushort& lo){
  h = rne_bf16(f);
  float r = f - bf2f(h);
  lo = (ushort)(__float_as_uint(r) >> 16);
}

// split 8 fp32 -> 8 bf16-hi (truncated) + 8 bf16-lo (of remainder), packed 2/word
__device__ __forceinline__ void split8(float4 fa, float4 fb, uint4& h, uint4& lo){
  uint a0=__float_as_uint(fa.x), a1=__float_as_uint(fa.y), a2=__float_as_uint(fa.z), a3=__float_as_uint(fa.w);
  uint b0=__float_as_uint(fb.x), b1=__float_as_uint(fb.y), b2=__float_as_uint(fb.z), b3=__float_as_uint(fb.w);
  h.x = (a0>>16) | (a1 & 0xFFFF0000u);
  h.y = (a2>>16) | (a3 & 0xFFFF0000u);
  h.z = (b0>>16) | (b1 & 0xFFFF0000u);
  h.w = (b2>>16) | (b3 & 0xFFFF0000u);
  float r0 = fa.x - __uint_as_float(a0 & 0xFFFF0000u);
  float r1 = fa.y - __uint_as_float(a1 & 0xFFFF0000u);
  float r2 = fa.z - __uint_as_float(a2 & 0xFFFF0000u);
  float r3 = fa.w - __uint_as_float(a3 & 0xFFFF0000u);
  float r4 = fb.x - __uint_as_float(b0 & 0xFFFF0000u);
  float r5 = fb.y - __uint_as_float(b1 & 0xFFFF0000u);
  float r6 = fb.z - __uint_as_float(b2 & 0xFFFF0000u);
  float r7 = fb.w - __uint_as_float(b3 & 0xFFFF0000u);
  lo.x = (__float_as_uint(r0)>>16) | (__float_as_uint(r1) & 0xFFFF0000u);
  lo.y = (__float_as_uint(r2)>>16) | (__float_as_uint(r3) & 0xFFFF0000u);
  lo.z = (__float_as_uint(r4)>>16) | (__float_as_uint(r5) & 0xFFFF0000u);
  lo.w = (__float_as_uint(r6)>>16) | (__float_as_uint(r7) & 0xFFFF0000u);
}

// ================= CSR build (counting sort of edges by dst) =================
__global__ void k_hist(const int* __restrict__ dst, int* __restrict__ cnt){
  int stride = gridDim.x * blockDim.x;
  for (int e = blockIdx.x*blockDim.x + threadIdx.x; e < NE; e += stride)
    atomicAdd(&cnt[dst[e]], 1);
}

__global__ void k_scan_block(const int* __restrict__ cnt, int* __restrict__ offs,
                             int* __restrict__ bsum){
  __shared__ int s[256];
  const int t = threadIdx.x, i = blockIdx.x*256 + t;
  int v = cnt[i];
  s[t] = v; __syncthreads();
  #pragma unroll
  for (int off = 1; off < 256; off <<= 1){
    int x = (t >= off) ? s[t-off] : 0;
    __syncthreads();
    s[t] += x;
    __syncthreads();
  }
  offs[i] = s[t] - v;
  if (t == 255) bsum[blockIdx.x] = s[255];
}

__global__ void k_scan_top(const int* __restrict__ bsum, int* __restrict__ bsum2){
  __shared__ int s[256];
  const int t = threadIdx.x;
  int v = (t < NSCAN) ? bsum[t] : 0;
  s[t] = v; __syncthreads();
  #pragma unroll
  for (int off = 1; off < 256; off <<= 1){
    int x = (t >= off) ? s[t-off] : 0;
    __syncthreads();
    s[t] += x;
    __syncthreads();
  }
  if (t < NSCAN) bsum2[t] = s[t] - v;
}

__global__ void k_scan_add(int* __restrict__ offs, const int* __restrict__ bsum2,
                           int* __restrict__ cursor){
  const int i = blockIdx.x*256 + threadIdx.x;
  int v = offs[i] + bsum2[blockIdx.x];
  offs[i] = v;
  cursor[i] = v;
}

__global__ void k_fill(const int* __restrict__ src, const int* __restrict__ dst,
                       int* __restrict__ cursor, int* __restrict__ csr){
  int stride = gridDim.x * blockDim.x;
  for (int e = blockIdx.x*blockDim.x + threadIdx.x; e < NE; e += stride){
    int d = dst[e];
    int pos = atomicAdd(&cursor[d], 1);
    csr[pos] = src[e];
  }
}

// ================= fp32 -> bf16 (RNE) bulk convert =================
__global__ void k_tobf16(const float* __restrict__ in, ushort* __restrict__ out){
  const int i = blockIdx.x*blockDim.x + threadIdx.x;   // one per 8 elems
  const float4 a = ((const float4*)in)[i*2];
  const float4 b = ((const float4*)in)[i*2+1];
  ushort o[8] = { rne_bf16(a.x), rne_bf16(a.y), rne_bf16(a.z), rne_bf16(a.w),
                  rne_bf16(b.x), rne_bf16(b.y), rne_bf16(b.z), rne_bf16(b.w) };
  ((uint4*)out)[i] = *(uint4*)o;
}

// ================= mean-aggregate gather over bf16 features =================
// Output written pre-split RNE-hi / residual-lo.
__launch_bounds__(256, 8)
__global__ void k_gather_bf16(const ushort* __restrict__ feat, const int* __restrict__ offs,
                              const int* __restrict__ csr,
                              ushort* __restrict__ outH, ushort* __restrict__ outL){
  __shared__ float4 sp[256];
  const int u = blockIdx.x, t = threadIdx.x;
  const int w = t >> 6, l = t & 63;
  const int beg = offs[u], end = offs[u+1];
  const int lc = l * 4;
  float a0 = 0.f, a1 = 0.f, a2 = 0.f, a3 = 0.f;
  int e = beg + w;
  for (; e + 4 < end; e += 8){
    int s0 = csr[e], s1 = csr[e+4];
    ushort4 v0 = *(const ushort4*)(feat + (long long)s0*ND + lc);
    ushort4 v1 = *(const ushort4*)(feat + (long long)s1*ND + lc);
    a0 += bf2f(v0.x) + bf2f(v1.x);
    a1 += bf2f(v0.y) + bf2f(v1.y);
    a2 += bf2f(v0.z) + bf2f(v1.z);
    a3 += bf2f(v0.w) + bf2f(v1.w);
  }
  if (e < end){
    int s0 = csr[e];
    ushort4 v0 = *(const ushort4*)(feat + (long long)s0*ND + lc);
    a0 += bf2f(v0.x); a1 += bf2f(v0.y); a2 += bf2f(v0.z); a3 += bf2f(v0.w);
  }
  sp[t] = make_float4(a0, a1, a2, a3);
  __syncthreads();
  if (t < 64){
    float4 p0 = sp[t], p1 = sp[64+t], p2 = sp[128+t], p3 = sp[192+t];
    float inv = 1.0f / fmaxf((float)(end - beg), 1.0f);
    float4 r;
    r.x = (p0.x + p1.x + p2.x + p3.x) * inv;
    r.y = (p0.y + p1.y + p2.y + p3.y) * inv;
    r.z = (p0.z + p1.z + p2.z + p3.z) * inv;
    r.w = (p0.w + p1.w + p2.w + p3.w) * inv;
    ushort hh[4], ll[4];
    splitr(r.x, hh[0], ll[0]);
    splitr(r.y, hh[1], ll[1]);
    splitr(r.z, hh[2], ll[2]);
    splitr(r.w, hh[3], ll[3]);
    *(ushort4*)(outH + (long long)u*ND + t*4) = *(ushort4*)hh;
    *(ushort4*)(outL + (long long)u*ND + t*4) = *(ushort4*)ll;
  }
}

// ============ weight prep: fragment-linear swizzled [wl; wr] bf16 hi/lo ============
__global__ void k_wsplit(const float* __restrict__ wl, const float* __restrict__ wr,
                         ushort* __restrict__ WtH, ushort* __restrict__ WtL){
  const int k = blockIdx.x;    // 0..511
  const int n = threadIdx.x;   // 0..255
  float v = (k < 256) ? wl[k*256 + n] : wr[(k-256)*256 + n];
  uint u = __float_as_uint(v);
  float r = v - __uint_as_float(u & 0xFFFF0000u);
  const int wc = n >> 6, nt = (n >> 4) & 3, lm = n & 15;
  const int kk = k >> 5, lq = (k >> 3) & 3, j = k & 7;
  const long long idx = (long long)(((wc*4 + nt)*16 + kk)*64 + lq*16 + lm)*8 + j;
  WtH[idx] = (ushort)(u >> 16);
  WtL[idx] = (ushort)(__float_as_uint(r) >> 16);
}

// ============ w_hh transpose: wT[k][row] so LSTM weight reads coalesce ============
__global__ void k_wtrans(const float* __restrict__ w_hh, float* __restrict__ wT){
  const int k = blockIdx.x;        // 0..255
  for (int r = threadIdx.x; r < 1024; r += 256)
    wT[(long long)k*1024 + r] = w_hh[(long long)r*256 + k];
}

// ============ unified MFMA SAGE GEMM: 64x256 tile, 1-D grid, pinned deep prefetch ============
template<int A2F32, int RELU>
__launch_bounds__(256, 2)
__global__ void k_gemm(const ushort* A1H, const ushort* A1L,
                       const ushort* A2H, const ushort* A2L,
                       const float*  A2F,
                       const ushort* __restrict__ WtH, const ushort* __restrict__ WtL,
                       const float* __restrict__ bias,
                       ushort* CH, ushort* CL)
{
  __shared__ float eb[16*260];          // 16.6 KB epilogue staging
  const int t  = threadIdx.x;
  const int w  = t >> 6;                // wave 0..3
  const int l  = t & 63;                // lane
  const int lm = l & 15;
  const int lq = l >> 4;
  const int m0 = blockIdx.x * 64;

  const uint4* BH4 = (const uint4*)WtH;
  const uint4* BL4 = (const uint4*)WtL;

  const float4v vzero = {0.f, 0.f, 0.f, 0.f};
  float4v acc[4][4];
  #pragma unroll
  for (int i = 0; i < 4; ++i)
    #pragma unroll
    for (int j = 0; j < 4; ++j) acc[i][j] = vzero;

  long long arow[4];
  #pragma unroll
  for (int mt = 0; mt < 4; ++mt){
    int row = m0 + mt*16 + lm;
    row = (row < NN) ? row : (NN - 1);  // clamp in-tile; dup rows discarded by store guard
    arow[mt] = (long long)row * ND;
  }
  int bbase[4];
  #pragma unroll
  for (int nt = 0; nt < 4; ++nt) bbase[nt] = (w*4 + nt)*1024 + l;

  uint4 aP[3][4], aQ[3][4];
  uint4 bh[2][4], bl[2][4];

  auto ldB = [&](int kk, int s){
    #pragma unroll
    for (int nt = 0; nt < 4; ++nt){
      const int idx = bbase[nt] + kk*64;
      bh[s][nt] = BH4[idx];
      bl[s][nt] = BL4[idx];
    }
  };
  auto ldA = [&](int kk, int s){
    const int koff = (kk & 7)*32 + lq*8;
    if (kk < 8 || !A2F32){
      const ushort* Hb = (kk < 8) ? A1H : A2H;
      const ushort* Lb = (kk < 8) ? A1L : A2L;
      #pragma unroll
      for (int mt = 0; mt < 4; ++mt){
        aP[s][mt] = *(const uint4*)(Hb + arow[mt] + koff);
        aQ[s][mt] = *(const uint4*)(Lb + arow[mt] + koff);
      }
    } else {
      #pragma unroll
      for (int mt = 0; mt < 4; ++mt){
        const float* p = A2F + arow[mt] + koff;
        aP[s][mt] = *(const uint4*)p;        // fa bits
        aQ[s][mt] = *(const uint4*)(p + 4);  // fb bits
      }
    }
  };

  ldA(0, 0);
  ldB(0, 0);
  ldA(1, 1);

  #pragma unroll
  for (int kk = 0; kk < 16; ++kk){
    const int c3 = kk % 3;
    const int cB = kk & 1;
    if (kk < 15) ldB(kk + 1, cB ^ 1);
    if (kk < 14) ldA(kk + 2, (kk + 2) % 3);
    __builtin_amdgcn_sched_barrier(0);   // pin: loads above may not sink past here

    uint4 ah[4], al[4];
    if (kk < 8 || !A2F32){
      #pragma unroll
      for (int mt = 0; mt < 4; ++mt){ ah[mt] = aP[c3][mt]; al[mt] = aQ[c3][mt]; }
    } else {
      #pragma unroll
      for (int mt = 0; mt < 4; ++mt){
        float4 fa = *(float4*)&aP[c3][mt];
        float4 fb = *(float4*)&aQ[c3][mt];
        split8(fa, fb, ah[mt], al[mt]);
      }
    }

    #pragma unroll
    for (int nt = 0; nt < 4; ++nt){
      short8v bhv = *(short8v*)&bh[cB][nt];
      short8v blv = *(short8v*)&bl[cB][nt];
      #pragma unroll
      for (int mt = 0; mt < 4; ++mt){
        short8v ahv = *(short8v*)&ah[mt];
        short8v alv = *(short8v*)&al[mt];
        acc[mt][nt] = __builtin_amdgcn_mfma_f32_16x16x32_bf16(ahv, bhv, acc[mt][nt], 0, 0, 0);
        acc[mt][nt] = __builtin_amdgcn_mfma_f32_16x16x32_bf16(alv, bhv, acc[mt][nt], 0, 0, 0);
        acc[mt][nt] = __builtin_amdgcn_mfma_f32_16x16x32_bf16(ahv, blv, acc[mt][nt], 0, 0, 0);
      }
    }
  }

  // ---- epilogue: LDS transpose per 16-row slab, coalesced RNE-hi/lo stores ----
  float bvv[4];
  #pragma unroll
  for (int nt = 0; nt < 4; ++nt) bvv[nt] = bias[w*64 + nt*16 + lm];

  #pragma unroll
  for (int mt = 0; mt < 4; ++mt){
    #pragma unroll
    for (int nt = 0; nt < 4; ++nt){
      #pragma unroll
      for (int r = 0; r < 4; ++r){
        float v = acc[mt][nt][r] + bvv[nt];
        if (RELU) v = fmaxf(v, 0.f);
        eb[(lq*4 + r)*260 + w*64 + nt*16 + lm] = v;   // C/D: col=lane&15, row=quad*4+reg
      }
    }
    __syncthreads();
    #pragma unroll
    for (int i = 0; i < 4; ++i){
      int idx = i*256 + t;           // 0..1023
      int rr  = idx >> 6;            // 0..15
      int c4  = (idx & 63) * 4;      // 0..252
      int grow = m0 + mt*16 + rr;
      if (grow < NN){
        float4 fv = *(float4*)&eb[rr*260 + c4];
        ushort hh[4], ll[4];
        splitr(fv.x, hh[0], ll[0]);
        splitr(fv.y, hh[1], ll[1]);
        splitr(fv.z, hh[2], ll[2]);
        splitr(fv.w, hh[3], ll[3]);
        *(ushort4*)(CH + (long long)grow*ND + c4) = *(ushort4*)hh;
        *(ushort4*)(CL + (long long)grow*ND + c4) = *(ushort4*)ll;
      }
    }
    __syncthreads();
  }
}

// ---------------- LSTM input gates ----------------
__launch_bounds__(256, 3)
__global__ void k_xgate(const ushort* __restrict__ EH, const ushort* __restrict__ EL,
                        const int* __restrict__ paths,
                        const float* __restrict__ w_ih, const float* __restrict__ b_ih,
                        const float* __restrict__ b_hh, float* __restrict__ xg)
{
  __shared__ float As[16][68];
  __shared__ float Ws[16][260];
  const int t  = threadIdx.x;
  const int m0 = blockIdx.x * 64;    // path rows (2048 total)
  const int g0 = blockIdx.y * 256;   // gate cols (1024 total)
  const int rg = t >> 5, cg = t & 31;
  const int sm = t >> 2, sj = (t & 3) * 4;

  float acc[8][8];
  #pragma unroll
  for (int i = 0; i < 8; ++i)
    #pragma unroll
    for (int j = 0; j < 8; ++j) acc[i][j] = 0.f;

  const int node = paths[m0 + sm];
  const ushort* ehrow = EH + (long long)node*ND;
  const ushort* elrow = EL + (long long)node*ND;
  const float* wrow = w_ih + (long long)(g0 + t)*ND;

  for (int k0 = 0; k0 < 256; k0 += 16){
    ushort4 hv = *(const ushort4*)(ehrow + k0 + sj);
    ushort4 lv = *(const ushort4*)(elrow + k0 + sj);
    float av0 = bf2f(hv.x) + bf2f(lv.x);
    float av1 = bf2f(hv.y) + bf2f(lv.y);
    float av2 = bf2f(hv.z) + bf2f(lv.z);
    float av3 = bf2f(hv.w) + bf2f(lv.w);
    float4 q0 = *(const float4*)(wrow + k0 + 0);
    float4 q1 = *(const float4*)(wrow + k0 + 4);
    float4 q2 = *(const float4*)(wrow + k0 + 8);
    float4 q3 = *(const float4*)(wrow + k0 + 12);
    __syncthreads();
    As[sj+0][sm]=av0; As[sj+1][sm]=av1; As[sj+2][sm]=av2; As[sj+3][sm]=av3;
    Ws[ 0][t]=q0.x; Ws[ 1][t]=q0.y; Ws[ 2][t]=q0.z; Ws[ 3][t]=q0.w;
    Ws[ 4][t]=q1.x; Ws[ 5][t]=q1.y; Ws[ 6][t]=q1.z; Ws[ 7][t]=q1.w;
    Ws[ 8][t]=q2.x; Ws[ 9][t]=q2.y; Ws[10][t]=q2.z; Ws[11][t]=q2.w;
    Ws[12][t]=q3.x; Ws[13][t]=q3.y; Ws[14][t]=q3.z; Ws[15][t]=q3.w;
    __syncthreads();
    #pragma unroll
    for (int k = 0; k < 16; ++k){
      float a[8], b[8];
      *(float4*)&a[0] = *(const float4*)&As[k][rg*8];
      *(float4*)&a[4] = *(const float4*)&As[k][rg*8+4];
      *(float4*)&b[0] = *(const float4*)&Ws[k][cg*8];
      *(float4*)&b[4] = *(const float4*)&Ws[k][cg*8+4];
      #pragma unroll
      for (int i = 0; i < 8; ++i)
        #pragma unroll
        for (int j = 0; j < 8; ++j)
          acc[i][j] = fmaf(a[i], b[j], acc[i][j]);
    }
  }

  float bv[8];
  #pragma unroll
  for (int j = 0; j < 8; ++j){ int g = g0 + cg*8 + j; bv[j] = b_ih[g] + b_hh[g]; }
  #pragma unroll
  for (int i = 0; i < 8; ++i){
    int row = m0 + rg*8 + i;
    float o[8];
    #pragma unroll
    for (int j = 0; j < 8; ++j) o[j] = acc[i][j] + bv[j];
    *(float4*)(xg + (long long)row*1024 + g0 + cg*8 + 0) = *(float4*)&o[0];
    *(float4*)(xg + (long long)row*1024 + g0 + cg*8 + 4) = *(float4*)&o[4];
  }
}

// ---------------- fused LSTM: one block per BATCH, transposed weights ----------------
// 64 blocks x 1024 threads; thread t = gate-row (gate*256+unit). Weight read is
// wT[k*1024 + t] -> consecutive lanes read consecutive addresses (coalesced, L2-hot;
// round-7's per-thread-row layout was 64 lines/wave -> 1083 us). h[k] is a
// conflict-free LDS broadcast. c[u] in a register of thread u. No cross-block comm.
// Summation order: two k-halves then +xg (matches the verified 32-launch version).
__launch_bounds__(1024, 4)
__global__ void k_lstm_batch(const float* __restrict__ xg, const float* __restrict__ wT,
                             float* __restrict__ hfin)
{
  __shared__ float hcur[256];
  __shared__ float gs[1024];
  const int t = threadIdx.x;          // = gate*256 + unit
  const int b = blockIdx.x;           // batch element
  float c_reg = 0.f;                  // thread t<256 owns c[unit=t]

  for (int ts = 0; ts < NL; ++ts){
    float s;
    if (ts == 0){
      s = 0.f;                        // h0 == 0 -> recurrent term vanishes
    } else {
      float s0 = 0.f, s1 = 0.f;
      #pragma unroll 8
      for (int k4 = 0; k4 < 32; ++k4){
        float4 h4 = *(const float4*)&hcur[k4*4];
        const float* wp = wT + (long long)(k4*4)*1024 + t;
        s0 += h4.x*wp[0] + h4.y*wp[1024] + h4.z*wp[2048] + h4.w*wp[3072];
      }
      #pragma unroll 8
      for (int k4 = 32; k4 < 64; ++k4){
        float4 h4 = *(const float4*)&hcur[k4*4];
        const float* wp = wT + (long long)(k4*4)*1024 + t;
        s1 += h4.x*wp[0] + h4.y*wp[1024] + h4.z*wp[2048] + h4.w*wp[3072];
      }
      s = s0 + s1;
    }
    s += xg[((long long)b*NL + ts)*1024 + t];
    gs[t] = s;
    __syncthreads();
    if (t < 256){
      float gi = gs[t], gf = gs[256+t], gG = gs[512+t], go = gs[768+t];
      float c_new = sigf(gf)*c_reg + sigf(gi)*tanhf(gG);
      c_reg = c_new;
      float h = sigf(go)*tanhf(c_new);
      hcur[t] = h;
      if (ts == NL-1) hfin[b*256 + t] = h;
    }
    __syncthreads();
  }
}

// ---------------- global mean pool (hi/lo bf16 input), chunk-parallel ----------------
__launch_bounds__(256, 8)
__global__ void k_pool(const ushort* __restrict__ EH, const ushort* __restrict__ EL,
                       const int* __restrict__ batch,
                       float* __restrict__ gsum, float* __restrict__ gcnt)
{
  __shared__ int bs[64];
  __shared__ int uni;
  __shared__ float spf[8*256];
  const int t  = threadIdx.x;
  const int m0 = blockIdx.x * 64;
  const int r  = t >> 5;        // row-lane 0..7
  const int c  = t & 31;        // colgroup 0..31 (8 elems each)
  if (t == 0) uni = 1;
  if (t < 64){
    int n = m0 + t;
    bs[t] = (n < NN) ? batch[n] : -1;
  }
  __syncthreads();
  if (t < 64 && bs[t] != bs[0]) uni = 0;
  __syncthreads();

  const ushort* eh = EH + (long long)m0*ND + c*8;
  const ushort* el = EL + (long long)m0*ND + c*8;

  if (uni){
    float a[8];
    #pragma unroll
    for (int j = 0; j < 8; ++j) a[j] = 0.f;
    #pragma unroll
    for (int i = 0; i < 8; ++i){
      const int row = r*8 + i;
      const uint4 hv = *(const uint4*)(eh + (long long)row*ND);
      const uint4 lv = *(const uint4*)(el + (long long)row*ND);
      const ushort* hp = (const ushort*)&hv;
      const ushort* lp = (const ushort*)&lv;
      #pragma unroll
      for (int j = 0; j < 8; ++j) a[j] += bf2f(hp[j]) + bf2f(lp[j]);
    }
    #pragma unroll
    for (int j = 0; j < 8; ++j) spf[r*256 + c*8 + j] = a[j];
    __syncthreads();
    float s = spf[t] + spf[256+t] + spf[512+t] + spf[768+t]
            + spf[1024+t] + spf[1280+t] + spf[1536+t] + spf[1792+t];
    const int g = bs[0];
    unsafeAtomicAdd(&gsum[g*256 + t], s);
    if (t == 0) unsafeAtomicAdd(&gcnt[g], 64.0f);
  } else {
    float a[8];
    #pragma unroll
    for (int j = 0; j < 8; ++j) a[j] = 0.f;
    int cur = -1, cnt = 0;
    #pragma unroll
    for (int i = 0; i < 8; ++i){
      const int row = r*8 + i;
      const int g = bs[row];
      if (g != cur){
        if (cur >= 0){
          #pragma unroll
          for (int j = 0; j < 8; ++j) unsafeAtomicAdd(&gsum[cur*256 + c*8 + j], a[j]);
          if (c == 0) unsafeAtomicAdd(&gcnt[cur], (float)cnt);
        }
        #pragma unroll
        for (int j = 0; j < 8; ++j) a[j] = 0.f;
        cnt = 0; cur = g;
      }
      if (g >= 0){
        const uint4 hv = *(const uint4*)(eh + (long long)row*ND);
        const uint4 lv = *(const uint4*)(el + (long long)row*ND);
        const ushort* hp = (const ushort*)&hv;
        const ushort* lp = (const ushort*)&lv;
        #pragma unroll
        for (int j = 0; j < 8; ++j) a[j] += bf2f(hp[j]) + bf2f(lp[j]);
        ++cnt;
      }
    }
    if (cur >= 0){
      #pragma unroll
      for (int j = 0; j < 8; ++j) unsafeAtomicAdd(&gsum[cur*256 + c*8 + j], a[j]);
      if (c == 0) unsafeAtomicAdd(&gcnt[cur], (float)cnt);
    }
  }
}

// ---------------- scorer MLP (pool-finalize + concat fused in) ----------------
__global__ void k_score(const float* __restrict__ gsum, const float* __restrict__ gcnt,
                        const float* __restrict__ hfin, const float* __restrict__ wm1,
                        const float* __restrict__ bm1, const float* __restrict__ wm2,
                        const float* __restrict__ bm2, float* __restrict__ out)
{
  __shared__ float cs[512];
  __shared__ float red[4];
  const int b = blockIdx.x, t = threadIdx.x;
  float inv = 1.0f / fmaxf(gcnt[b], 1.0f);
  cs[t]       = gsum[b*256 + t] * inv;
  cs[256 + t] = hfin[b*256 + t];
  __syncthreads();
  float v = 0.f;
  #pragma unroll 4
  for (int k = 0; k < 512; ++k) v = fmaf(cs[k], wm1[(long long)k*256 + t], v);
  v = fmaxf(v + bm1[t], 0.f) * wm2[t];
  #pragma unroll
  for (int off = 32; off > 0; off >>= 1) v += __shfl_down(v, off, 64);
  if ((t & 63) == 0) red[t >> 6] = v;
  __syncthreads();
  if (t == 0) out[b] = red[0] + red[1] + red[2] + red[3] + bm2[0];
}

} // namespace

extern "C" void kernel_launch(void* const* d_in, const int* in_sizes, int n_in,
                              void* d_out, int out_size, void* d_ws, size_t ws_size,
                              hipStream_t stream)
{
  const float* x     = (const float*)d_in[0];
  const int*   eidx  = (const int*)  d_in[1];
  const int*   batch = (const int*)  d_in[2];
  const int*   paths = (const int*)  d_in[3];
  const float* w1l   = (const float*)d_in[4];
  const float* b1l   = (const float*)d_in[5];
  const float* w1r   = (const float*)d_in[6];
  const float* w2l   = (const float*)d_in[7];
  const float* b2l   = (const float*)d_in[8];
  const float* w2r   = (const float*)d_in[9];
  const float* w_ih  = (const float*)d_in[10];
  const float* w_hh  = (const float*)d_in[11];
  const float* b_ih  = (const float*)d_in[12];
  const float* b_hh  = (const float*)d_in[13];
  const float* wm1   = (const float*)d_in[14];
  const float* bm1   = (const float*)d_in[15];
  const float* wm2   = (const float*)d_in[16];
  const float* bm2   = (const float*)d_in[17];

  const int* src = eidx;        // edge_index[0]
  const int* dst = eidx + NE;   // edge_index[1]

  // workspace layout (same footprint as the original session, ~138 MB)
  float* w    = (float*)d_ws;
  float* bufA = w;                         // region0: gather out hi/lo; later wT (1 MB)
  float* bufB = bufA + (long long)NN*ND;   // region1: h1 hi/lo -> node_emb hi/lo (in-place)
  float* xg   = bufB + (long long)NN*ND;   // 2048*1024 floats
  float* gsum = xg   + 2048*1024;          // 64*256
  float* gcnt = gsum + NB*ND;              // 64
  float* h0   = gcnt + 64;                 // 64*256 (final hidden state)
  float* c0   = h0   + NB*ND;              // 64*256 (unused; c lives in registers)
  float* h1   = c0   + NB*ND;              // 64*256 (unused)
  ushort* wt1H = (ushort*)(h1 + NB*ND);    // 256*512 each (bf16, fragment-swizzled)
  ushort* wt1L = wt1H + 256*512;
  ushort* wt2H = wt1L + 256*512;
  ushort* wt2L = wt2H + 256*512;
  ushort* fb16 = wt2L + 256*512;           // N*256 bf16: x RNE copy (gather-1 input)

  ushort* A1H = (ushort*)bufA;             // gather mean, hi
  ushort* A1L = A1H + (long long)NN*ND;    // gather mean, lo
  ushort* h1H = (ushort*)bufB;             // h1 RNE-hi (layer1 out) -> node_emb hi (layer2, in-place)
  ushort* h1L = h1H + (long long)NN*ND;    // h1 residual-lo       -> node_emb lo
  float*  wT  = bufA;                      // 256*1024 floats; aliased: bufA dead after GEMM-2

  // CSR scratch aliased into xg region (dead until k_xgate runs, after layer 2)
  int* cnt    = (int*)xg;        // 50432
  int* offs   = cnt    + 50432;  // 50432
  int* cursor = offs   + 50432;  // 50432
  int* bsum   = cursor + 50432;  // 256
  int* bsum2  = bsum   + 256;    // 256
  int* csr    = bsum2  + 256;    // 800000

  // ---- weight prep (fragment-swizzled bf16 hi/lo split) ----
  k_wsplit<<<512, 256, 0, stream>>>(w1l, w1r, wt1H, wt1L);
  k_wsplit<<<512, 256, 0, stream>>>(w2l, w2r, wt2H, wt2L);

  // ---- x -> bf16 RNE copy (gather-1 input) ----
  k_tobf16<<<(NN*ND/8 + 255)/256, 256, 0, stream>>>(x, fb16);

  // ---- build CSR (counting sort by dst), shared by both layers ----
  hipMemsetAsync(cnt, 0, 50432*sizeof(int), stream);
  k_hist<<<1024, 256, 0, stream>>>(dst, cnt);
  k_scan_block<<<NSCAN, 256, 0, stream>>>(cnt, offs, bsum);
  k_scan_top<<<1, 256, 0, stream>>>(bsum, bsum2);
  k_scan_add<<<NSCAN, 256, 0, stream>>>(offs, bsum2, cursor);
  k_fill<<<1024, 256, 0, stream>>>(src, dst, cursor, csr);

  // ---- layer 1: gather-mean (pre-split); GEMM A2 = x fp32 (alias-free), relu ----
  k_gather_bf16<<<NN, 256, 0, stream>>>(fb16, offs, csr, A1H, A1L);
  k_gemm<1,1><<<782, 256, 0, stream>>>(A1H, A1L, nullptr, nullptr, x,
                                       wt1H, wt1L, b1l, h1H, h1L);

  // ---- layer 2: gather over RNE(relu(h1)) = h1H; GEMM all-pre-split, in-place ----
  k_gather_bf16<<<NN, 256, 0, stream>>>(h1H, offs, csr, A1H, A1L);
  k_gemm<0,0><<<782, 256, 0, stream>>>(A1H, A1L, h1H, h1L, nullptr,
                                       wt2H, wt2L, b2l, h1H, h1L);

  // ---- w_hh transpose (bufA region now dead -> holds wT) ----
  k_wtrans<<<256, 256, 0, stream>>>(w_hh, wT);

  // ---- global mean pool (chunk-parallel, vectorized) ----
  hipMemsetAsync(gsum, 0, (NB*ND + 64)*sizeof(float), stream);
  k_pool<<<NPOOL, 256, 0, stream>>>(h1H, h1L, batch, gsum, gcnt);

  // ---- LSTM input gates (overwrites the CSR alias region — CSR dead by now) ----
  k_xgate<<<dim3((NB*NL)/64, 1024/256), 256, 0, stream>>>(h1H, h1L, paths, w_ih, b_ih, b_hh, xg);

  // ---- LSTM recurrence: ONE launch, one block per independent batch sequence ----
  k_lstm_batch<<<NB, 1024, 0, stream>>>(xg, wT, h0);
  // h0 = final hidden state

  // ---- fused concat + scorer ----
  k_score<<<NB, 256, 0, stream>>>(gsum, gcnt, h0, wm1, bm1, wm2, bm2, (float*)d_out);
}

// Round 9
// 923.041 us; speedup vs baseline: 1.8559x; 1.0485x over previous
//
#include <hip/hip_runtime.h>

namespace {

constexpr int NN = 50000;   // nodes
constexpr int NE = 800000;  // edges
constexpr int NB = 64;      // graphs / batch
constexpr int NL = 32;      // path length
constexpr int ND = 256;     // D == H == 256
constexpr int NSCAN = 196;  // ceil(50176/256) scan blocks
constexpr int NPOOL = (NN + 63) / 64;  // 782 pool blocks

typedef __attribute__((ext_vector_type(8))) short short8v;  // 8 bf16 (4 VGPRs)
typedef __attribute__((ext_vector_type(4))) float float4v;  // MFMA accumulator

__device__ __forceinline__ float sigf(float x){ return 1.0f/(1.0f + __expf(-x)); }

__device__ __forceinline__ ushort rne_bf16(float f){
  uint u = __float_as_uint(f);
  return (ushort)((u + 0x7FFFu + ((u >> 16) & 1u)) >> 16);
}
__device__ __forceinline__ float bf2f(ushort u){ return __uint_as_float((uint)u << 16); }

// hi = RNE-bf16(f), lo = trunc-bf16(f - hi)
__device__ __forceinline__ void splitr(float f, ushort& h, ushort& lo){
  h = rne_bf16(f);
  float r = f - bf2f(h);
  lo = (ushort)(__float_as_uint(r) >> 16);
}

// split 8 fp32 -> 8 bf16-hi (truncated) + 8 bf16-lo (of remainder), packed 2/word
__device__ __forceinline__ void split8(float4 fa, float4 fb, uint4& h, uint4& lo){
  uint a0=__float_as_uint(fa.x), a1=__float_as_uint(fa.y), a2=__float_as_uint(fa.z), a3=__float_as_uint(fa.w);
  uint b0=__float_as_uint(fb.x), b1=__float_as_uint(fb.y), b2=__float_as_uint(fb.z), b3=__float_as_uint(fb.w);
  h.x = (a0>>16) | (a1 & 0xFFFF0000u);
  h.y = (a2>>16) | (a3 & 0xFFFF0000u);
  h.z = (b0>>16) | (b1 & 0xFFFF0000u);
  h.w = (b2>>16) | (b3 & 0xFFFF0000u);
  float r0 = fa.x - __uint_as_float(a0 & 0xFFFF0000u);
  float r1 = fa.y - __uint_as_float(a1 & 0xFFFF0000u);
  float r2 = fa.z - __uint_as_float(a2 & 0xFFFF0000u);
  float r3 = fa.w - __uint_as_float(a3 & 0xFFFF0000u);
  float r4 = fb.x - __uint_as_float(b0 & 0xFFFF0000u);
  float r5 = fb.y - __uint_as_float(b1 & 0xFFFF0000u);
  float r6 = fb.z - __uint_as_float(b2 & 0xFFFF0000u);
  float r7 = fb.w - __uint_as_float(b3 & 0xFFFF0000u);
  lo.x = (__float_as_uint(r0)>>16) | (__float_as_uint(r1) & 0xFFFF0000u);
  lo.y = (__float_as_uint(r2)>>16) | (__float_as_uint(r3) & 0xFFFF0000u);
  lo.z = (__float_as_uint(r4)>>16) | (__float_as_uint(r5) & 0xFFFF0000u);
  lo.w = (__float_as_uint(r6)>>16) | (__float_as_uint(r7) & 0xFFFF0000u);
}

// ================= CSR build (counting sort of edges by dst) =================
__global__ void k_hist(const int* __restrict__ dst, int* __restrict__ cnt){
  int stride = gridDim.x * blockDim.x;
  for (int e = blockIdx.x*blockDim.x + threadIdx.x; e < NE; e += stride)
    atomicAdd(&cnt[dst[e]], 1);
}

__global__ void k_scan_block(const int* __restrict__ cnt, int* __restrict__ offs,
                             int* __restrict__ bsum){
  __shared__ int s[256];
  const int t = threadIdx.x, i = blockIdx.x*256 + t;
  int v = cnt[i];
  s[t] = v; __syncthreads();
  #pragma unroll
  for (int off = 1; off < 256; off <<= 1){
    int x = (t >= off) ? s[t-off] : 0;
    __syncthreads();
    s[t] += x;
    __syncthreads();
  }
  offs[i] = s[t] - v;
  if (t == 255) bsum[blockIdx.x] = s[255];
}

__global__ void k_scan_top(const int* __restrict__ bsum, int* __restrict__ bsum2){
  __shared__ int s[256];
  const int t = threadIdx.x;
  int v = (t < NSCAN) ? bsum[t] : 0;
  s[t] = v; __syncthreads();
  #pragma unroll
  for (int off = 1; off < 256; off <<= 1){
    int x = (t >= off) ? s[t-off] : 0;
    __syncthreads();
    s[t] += x;
    __syncthreads();
  }
  if (t < NSCAN) bsum2[t] = s[t] - v;
}

__global__ void k_scan_add(int* __restrict__ offs, const int* __restrict__ bsum2,
                           int* __restrict__ cursor){
  const int i = blockIdx.x*256 + threadIdx.x;
  int v = offs[i] + bsum2[blockIdx.x];
  offs[i] = v;
  cursor[i] = v;
}

__global__ void k_fill(const int* __restrict__ src, const int* __restrict__ dst,
                       int* __restrict__ cursor, int* __restrict__ csr){
  int stride = gridDim.x * blockDim.x;
  for (int e = blockIdx.x*blockDim.x + threadIdx.x; e < NE; e += stride){
    int d = dst[e];
    int pos = atomicAdd(&cursor[d], 1);
    csr[pos] = src[e];
  }
}

// ================= fp32 -> bf16 (RNE) bulk convert =================
__global__ void k_tobf16(const float* __restrict__ in, ushort* __restrict__ out){
  const int i = blockIdx.x*blockDim.x + threadIdx.x;   // one per 8 elems
  const float4 a = ((const float4*)in)[i*2];
  const float4 b = ((const float4*)in)[i*2+1];
  ushort o[8] = { rne_bf16(a.x), rne_bf16(a.y), rne_bf16(a.z), rne_bf16(a.w),
                  rne_bf16(b.x), rne_bf16(b.y), rne_bf16(b.z), rne_bf16(b.w) };
  ((uint4*)out)[i] = *(uint4*)o;
}

// ================= mean-aggregate gather over bf16 features =================
// Output written pre-split RNE-hi / residual-lo.
__launch_bounds__(256, 8)
__global__ void k_gather_bf16(const ushort* __restrict__ feat, const int* __restrict__ offs,
                              const int* __restrict__ csr,
                              ushort* __restrict__ outH, ushort* __restrict__ outL){
  __shared__ float4 sp[256];
  const int u = blockIdx.x, t = threadIdx.x;
  const int w = t >> 6, l = t & 63;
  const int beg = offs[u], end = offs[u+1];
  const int lc = l * 4;
  float a0 = 0.f, a1 = 0.f, a2 = 0.f, a3 = 0.f;
  int e = beg + w;
  for (; e + 4 < end; e += 8){
    int s0 = csr[e], s1 = csr[e+4];
    ushort4 v0 = *(const ushort4*)(feat + (long long)s0*ND + lc);
    ushort4 v1 = *(const ushort4*)(feat + (long long)s1*ND + lc);
    a0 += bf2f(v0.x) + bf2f(v1.x);
    a1 += bf2f(v0.y) + bf2f(v1.y);
    a2 += bf2f(v0.z) + bf2f(v1.z);
    a3 += bf2f(v0.w) + bf2f(v1.w);
  }
  if (e < end){
    int s0 = csr[e];
    ushort4 v0 = *(const ushort4*)(feat + (long long)s0*ND + lc);
    a0 += bf2f(v0.x); a1 += bf2f(v0.y); a2 += bf2f(v0.z); a3 += bf2f(v0.w);
  }
  sp[t] = make_float4(a0, a1, a2, a3);
  __syncthreads();
  if (t < 64){
    float4 p0 = sp[t], p1 = sp[64+t], p2 = sp[128+t], p3 = sp[192+t];
    float inv = 1.0f / fmaxf((float)(end - beg), 1.0f);
    float4 r;
    r.x = (p0.x + p1.x + p2.x + p3.x) * inv;
    r.y = (p0.y + p1.y + p2.y + p3.y) * inv;
    r.z = (p0.z + p1.z + p2.z + p3.z) * inv;
    r.w = (p0.w + p1.w + p2.w + p3.w) * inv;
    ushort hh[4], ll[4];
    splitr(r.x, hh[0], ll[0]);
    splitr(r.y, hh[1], ll[1]);
    splitr(r.z, hh[2], ll[2]);
    splitr(r.w, hh[3], ll[3]);
    *(ushort4*)(outH + (long long)u*ND + t*4) = *(ushort4*)hh;
    *(ushort4*)(outL + (long long)u*ND + t*4) = *(ushort4*)ll;
  }
}

// ============ weight prep: fragment-linear swizzled [wl; wr] bf16 hi/lo ============
__global__ void k_wsplit(const float* __restrict__ wl, const float* __restrict__ wr,
                         ushort* __restrict__ WtH, ushort* __restrict__ WtL){
  const int k = blockIdx.x;    // 0..511
  const int n = threadIdx.x;   // 0..255
  float v = (k < 256) ? wl[k*256 + n] : wr[(k-256)*256 + n];
  uint u = __float_as_uint(v);
  float r = v - __uint_as_float(u & 0xFFFF0000u);
  const int wc = n >> 6, nt = (n >> 4) & 3, lm = n & 15;
  const int kk = k >> 5, lq = (k >> 3) & 3, j = k & 7;
  const long long idx = (long long)(((wc*4 + nt)*16 + kk)*64 + lq*16 + lm)*8 + j;
  WtH[idx] = (ushort)(u >> 16);
  WtL[idx] = (ushort)(__float_as_uint(r) >> 16);
}

// ============ w_hh transpose, k-packed float4: wT4[k4*1024 + row] = w[row][4k4..4k4+3] ============
// LSTM weight read becomes ONE float4 per k4 per thread (coalesced 16B/lane), 4x fewer
// load instructions than the k-major scalar layout (round-8's 313us was load-issue-bound).
__global__ void k_wtrans(const float* __restrict__ w_hh, float4* __restrict__ wT4){
  const int k4 = blockIdx.x;       // 0..63
  for (int r = threadIdx.x; r < 1024; r += 256){
    const float* p = w_hh + (long long)r*256 + k4*4;
    wT4[(long long)k4*1024 + r] = make_float4(p[0], p[1], p[2], p[3]);
  }
}

// ============ unified MFMA SAGE GEMM: 64x256 tile, 1-D grid, pinned deep prefetch ============
template<int A2F32, int RELU>
__launch_bounds__(256, 2)
__global__ void k_gemm(const ushort* A1H, const ushort* A1L,
                       const ushort* A2H, const ushort* A2L,
                       const float*  A2F,
                       const ushort* __restrict__ WtH, const ushort* __restrict__ WtL,
                       const float* __restrict__ bias,
                       ushort* CH, ushort* CL)
{
  __shared__ float eb[16*260];          // 16.6 KB epilogue staging
  const int t  = threadIdx.x;
  const int w  = t >> 6;                // wave 0..3
  const int l  = t & 63;                // lane
  const int lm = l & 15;
  const int lq = l >> 4;
  const int m0 = blockIdx.x * 64;

  const uint4* BH4 = (const uint4*)WtH;
  const uint4* BL4 = (const uint4*)WtL;

  const float4v vzero = {0.f, 0.f, 0.f, 0.f};
  float4v acc[4][4];
  #pragma unroll
  for (int i = 0; i < 4; ++i)
    #pragma unroll
    for (int j = 0; j < 4; ++j) acc[i][j] = vzero;

  long long arow[4];
  #pragma unroll
  for (int mt = 0; mt < 4; ++mt){
    int row = m0 + mt*16 + lm;
    row = (row < NN) ? row : (NN - 1);  // clamp in-tile; dup rows discarded by store guard
    arow[mt] = (long long)row * ND;
  }
  int bbase[4];
  #pragma unroll
  for (int nt = 0; nt < 4; ++nt) bbase[nt] = (w*4 + nt)*1024 + l;

  uint4 aP[3][4], aQ[3][4];
  uint4 bh[2][4], bl[2][4];

  auto ldB = [&](int kk, int s){
    #pragma unroll
    for (int nt = 0; nt < 4; ++nt){
      const int idx = bbase[nt] + kk*64;
      bh[s][nt] = BH4[idx];
      bl[s][nt] = BL4[idx];
    }
  };
  auto ldA = [&](int kk, int s){
    const int koff = (kk & 7)*32 + lq*8;
    if (kk < 8 || !A2F32){
      const ushort* Hb = (kk < 8) ? A1H : A2H;
      const ushort* Lb = (kk < 8) ? A1L : A2L;
      #pragma unroll
      for (int mt = 0; mt < 4; ++mt){
        aP[s][mt] = *(const uint4*)(Hb + arow[mt] + koff);
        aQ[s][mt] = *(const uint4*)(Lb + arow[mt] + koff);
      }
    } else {
      #pragma unroll
      for (int mt = 0; mt < 4; ++mt){
        const float* p = A2F + arow[mt] + koff;
        aP[s][mt] = *(const uint4*)p;        // fa bits
        aQ[s][mt] = *(const uint4*)(p + 4);  // fb bits
      }
    }
  };

  ldA(0, 0);
  ldB(0, 0);
  ldA(1, 1);

  #pragma unroll
  for (int kk = 0; kk < 16; ++kk){
    const int c3 = kk % 3;
    const int cB = kk & 1;
    if (kk < 15) ldB(kk + 1, cB ^ 1);
    if (kk < 14) ldA(kk + 2, (kk + 2) % 3);
    __builtin_amdgcn_sched_barrier(0);   // pin: loads above may not sink past here

    uint4 ah[4], al[4];
    if (kk < 8 || !A2F32){
      #pragma unroll
      for (int mt = 0; mt < 4; ++mt){ ah[mt] = aP[c3][mt]; al[mt] = aQ[c3][mt]; }
    } else {
      #pragma unroll
      for (int mt = 0; mt < 4; ++mt){
        float4 fa = *(float4*)&aP[c3][mt];
        float4 fb = *(float4*)&aQ[c3][mt];
        split8(fa, fb, ah[mt], al[mt]);
      }
    }

    #pragma unroll
    for (int nt = 0; nt < 4; ++nt){
      short8v bhv = *(short8v*)&bh[cB][nt];
      short8v blv = *(short8v*)&bl[cB][nt];
      #pragma unroll
      for (int mt = 0; mt < 4; ++mt){
        short8v ahv = *(short8v*)&ah[mt];
        short8v alv = *(short8v*)&al[mt];
        acc[mt][nt] = __builtin_amdgcn_mfma_f32_16x16x32_bf16(ahv, bhv, acc[mt][nt], 0, 0, 0);
        acc[mt][nt] = __builtin_amdgcn_mfma_f32_16x16x32_bf16(alv, bhv, acc[mt][nt], 0, 0, 0);
        acc[mt][nt] = __builtin_amdgcn_mfma_f32_16x16x32_bf16(ahv, blv, acc[mt][nt], 0, 0, 0);
      }
    }
  }

  // ---- epilogue: LDS transpose per 16-row slab, coalesced RNE-hi/lo stores ----
  float bvv[4];
  #pragma unroll
  for (int nt = 0; nt < 4; ++nt) bvv[nt] = bias[w*64 + nt*16 + lm];

  #pragma unroll
  for (int mt = 0; mt < 4; ++mt){
    #pragma unroll
    for (int nt = 0; nt < 4; ++nt){
      #pragma unroll
      for (int r = 0; r < 4; ++r){
        float v = acc[mt][nt][r] + bvv[nt];
        if (RELU) v = fmaxf(v, 0.f);
        eb[(lq*4 + r)*260 + w*64 + nt*16 + lm] = v;   // C/D: col=lane&15, row=quad*4+reg
      }
    }
    __syncthreads();
    #pragma unroll
    for (int i = 0; i < 4; ++i){
      int idx = i*256 + t;           // 0..1023
      int rr  = idx >> 6;            // 0..15
      int c4  = (idx & 63) * 4;      // 0..252
      int grow = m0 + mt*16 + rr;
      if (grow < NN){
        float4 fv = *(float4*)&eb[rr*260 + c4];
        ushort hh[4], ll[4];
        splitr(fv.x, hh[0], ll[0]);
        splitr(fv.y, hh[1], ll[1]);
        splitr(fv.z, hh[2], ll[2]);
        splitr(fv.w, hh[3], ll[3]);
        *(ushort4*)(CH + (long long)grow*ND + c4) = *(ushort4*)hh;
        *(ushort4*)(CL + (long long)grow*ND + c4) = *(ushort4*)ll;
      }
    }
    __syncthreads();
  }
}

// ---------------- LSTM input gates ----------------
__launch_bounds__(256, 3)
__global__ void k_xgate(const ushort* __restrict__ EH, const ushort* __restrict__ EL,
                        const int* __restrict__ paths,
                        const float* __restrict__ w_ih, const float* __restrict__ b_ih,
                        const float* __restrict__ b_hh, float* __restrict__ xg)
{
  __shared__ float As[16][68];
  __shared__ float Ws[16][260];
  const int t  = threadIdx.x;
  const int m0 = blockIdx.x * 64;    // path rows (2048 total)
  const int g0 = blockIdx.y * 256;   // gate cols (1024 total)
  const int rg = t >> 5, cg = t & 31;
  const int sm = t >> 2, sj = (t & 3) * 4;

  float acc[8][8];
  #pragma unroll
  for (int i = 0; i < 8; ++i)
    #pragma unroll
    for (int j = 0; j < 8; ++j) acc[i][j] = 0.f;

  const int node = paths[m0 + sm];
  const ushort* ehrow = EH + (long long)node*ND;
  const ushort* elrow = EL + (long long)node*ND;
  const float* wrow = w_ih + (long long)(g0 + t)*ND;

  for (int k0 = 0; k0 < 256; k0 += 16){
    ushort4 hv = *(const ushort4*)(ehrow + k0 + sj);
    ushort4 lv = *(const ushort4*)(elrow + k0 + sj);
    float av0 = bf2f(hv.x) + bf2f(lv.x);
    float av1 = bf2f(hv.y) + bf2f(lv.y);
    float av2 = bf2f(hv.z) + bf2f(lv.z);
    float av3 = bf2f(hv.w) + bf2f(lv.w);
    float4 q0 = *(const float4*)(wrow + k0 + 0);
    float4 q1 = *(const float4*)(wrow + k0 + 4);
    float4 q2 = *(const float4*)(wrow + k0 + 8);
    float4 q3 = *(const float4*)(wrow + k0 + 12);
    __syncthreads();
    As[sj+0][sm]=av0; As[sj+1][sm]=av1; As[sj+2][sm]=av2; As[sj+3][sm]=av3;
    Ws[ 0][t]=q0.x; Ws[ 1][t]=q0.y; Ws[ 2][t]=q0.z; Ws[ 3][t]=q0.w;
    Ws[ 4][t]=q1.x; Ws[ 5][t]=q1.y; Ws[ 6][t]=q1.z; Ws[ 7][t]=q1.w;
    Ws[ 8][t]=q2.x; Ws[ 9][t]=q2.y; Ws[10][t]=q2.z; Ws[11][t]=q2.w;
    Ws[12][t]=q3.x; Ws[13][t]=q3.y; Ws[14][t]=q3.z; Ws[15][t]=q3.w;
    __syncthreads();
    #pragma unroll
    for (int k = 0; k < 16; ++k){
      float a[8], b[8];
      *(float4*)&a[0] = *(const float4*)&As[k][rg*8];
      *(float4*)&a[4] = *(const float4*)&As[k][rg*8+4];
      *(float4*)&b[0] = *(const float4*)&Ws[k][cg*8];
      *(float4*)&b[4] = *(const float4*)&Ws[k][cg*8+4];
      #pragma unroll
      for (int i = 0; i < 8; ++i)
        #pragma unroll
        for (int j = 0; j < 8; ++j)
          acc[i][j] = fmaf(a[i], b[j], acc[i][j]);
    }
  }

  float bv[8];
  #pragma unroll
  for (int j = 0; j < 8; ++j){ int g = g0 + cg*8 + j; bv[j] = b_ih[g] + b_hh[g]; }
  #pragma unroll
  for (int i = 0; i < 8; ++i){
    int row = m0 + rg*8 + i;
    float o[8];
    #pragma unroll
    for (int j = 0; j < 8; ++j) o[j] = acc[i][j] + bv[j];
    *(float4*)(xg + (long long)row*1024 + g0 + cg*8 + 0) = *(float4*)&o[0];
    *(float4*)(xg + (long long)row*1024 + g0 + cg*8 + 4) = *(float4*)&o[4];
  }
}

// ---------------- fused LSTM: one block per BATCH, k-packed float4 weights ----------------
// 64 blocks x 1024 threads; thread t = gate-row (gate*256+unit). Weight read is ONE
// coalesced float4 per k4: wT4[k4*1024 + t] = w[t][4k4..4k4+3] (matches the h4 LDS read).
// 64 load instrs/thread/step vs round-8's 256 (load-issue-bound at 313us). c[u] in a
// register of thread u; no cross-block comm. Dot order identical to round-8 (passed).
__launch_bounds__(1024, 4)
__global__ void k_lstm_batch(const float* __restrict__ xg, const float4* __restrict__ wT4,
                             float* __restrict__ hfin)
{
  __shared__ float hcur[256];
  __shared__ float gs[1024];
  const int t = threadIdx.x;          // = gate*256 + unit
  const int b = blockIdx.x;           // batch element
  const float4* wp = wT4 + t;         // element k4 at wp[k4*1024]
  float c_reg = 0.f;                  // thread t<256 owns c[unit=t]

  for (int ts = 0; ts < NL; ++ts){
    float s;
    if (ts == 0){
      s = 0.f;                        // h0 == 0 -> recurrent term vanishes
    } else {
      float s0 = 0.f, s1 = 0.f;
      #pragma unroll 8
      for (int k4 = 0; k4 < 32; ++k4){
        float4 h4 = *(const float4*)&hcur[k4*4];
        float4 w4 = wp[(long long)k4*1024];
        s0 += h4.x*w4.x + h4.y*w4.y + h4.z*w4.z + h4.w*w4.w;
      }
      #pragma unroll 8
      for (int k4 = 32; k4 < 64; ++k4){
        float4 h4 = *(const float4*)&hcur[k4*4];
        float4 w4 = wp[(long long)k4*1024];
        s1 += h4.x*w4.x + h4.y*w4.y + h4.z*w4.z + h4.w*w4.w;
      }
      s = s0 + s1;
    }
    s += xg[((long long)b*NL + ts)*1024 + t];
    gs[t] = s;
    __syncthreads();
    if (t < 256){
      float gi = gs[t], gf = gs[256+t], gG = gs[512+t], go = gs[768+t];
      float c_new = sigf(gf)*c_reg + sigf(gi)*tanhf(gG);
      c_reg = c_new;
      float h = sigf(go)*tanhf(c_new);
      hcur[t] = h;
      if (ts == NL-1) hfin[b*256 + t] = h;
    }
    __syncthreads();
  }
}

// ---------------- global mean pool (hi/lo bf16 input), chunk-parallel ----------------
__launch_bounds__(256, 8)
__global__ void k_pool(const ushort* __restrict__ EH, const ushort* __restrict__ EL,
                       const int* __restrict__ batch,
                       float* __restrict__ gsum, float* __restrict__ gcnt)
{
  __shared__ int bs[64];
  __shared__ int uni;
  __shared__ float spf[8*256];
  const int t  = threadIdx.x;
  const int m0 = blockIdx.x * 64;
  const int r  = t >> 5;        // row-lane 0..7
  const int c  = t & 31;        // colgroup 0..31 (8 elems each)
  if (t == 0) uni = 1;
  if (t < 64){
    int n = m0 + t;
    bs[t] = (n < NN) ? batch[n] : -1;
  }
  __syncthreads();
  if (t < 64 && bs[t] != bs[0]) uni = 0;
  __syncthreads();

  const ushort* eh = EH + (long long)m0*ND + c*8;
  const ushort* el = EL + (long long)m0*ND + c*8;

  if (uni){
    float a[8];
    #pragma unroll
    for (int j = 0; j < 8; ++j) a[j] = 0.f;
    #pragma unroll
    for (int i = 0; i < 8; ++i){
      const int row = r*8 + i;
      const uint4 hv = *(const uint4*)(eh + (long long)row*ND);
      const uint4 lv = *(const uint4*)(el + (long long)row*ND);
      const ushort* hp = (const ushort*)&hv;
      const ushort* lp = (const ushort*)&lv;
      #pragma unroll
      for (int j = 0; j < 8; ++j) a[j] += bf2f(hp[j]) + bf2f(lp[j]);
    }
    #pragma unroll
    for (int j = 0; j < 8; ++j) spf[r*256 + c*8 + j] = a[j];
    __syncthreads();
    float s = spf[t] + spf[256+t] + spf[512+t] + spf[768+t]
            + spf[1024+t] + spf[1280+t] + spf[1536+t] + spf[1792+t];
    const int g = bs[0];
    unsafeAtomicAdd(&gsum[g*256 + t], s);
    if (t == 0) unsafeAtomicAdd(&gcnt[g], 64.0f);
  } else {
    float a[8];
    #pragma unroll
    for (int j = 0; j < 8; ++j) a[j] = 0.f;
    int cur = -1, cnt = 0;
    #pragma unroll
    for (int i = 0; i < 8; ++i){
      const int row = r*8 + i;
      const int g = bs[row];
      if (g != cur){
        if (cur >= 0){
          #pragma unroll
          for (int j = 0; j < 8; ++j) unsafeAtomicAdd(&gsum[cur*256 + c*8 + j], a[j]);
          if (c == 0) unsafeAtomicAdd(&gcnt[cur], (float)cnt);
        }
        #pragma unroll
        for (int j = 0; j < 8; ++j) a[j] = 0.f;
        cnt = 0; cur = g;
      }
      if (g >= 0){
        const uint4 hv = *(const uint4*)(eh + (long long)row*ND);
        const uint4 lv = *(const uint4*)(el + (long long)row*ND);
        const ushort* hp = (const ushort*)&hv;
        const ushort* lp = (const ushort*)&lv;
        #pragma unroll
        for (int j = 0; j < 8; ++j) a[j] += bf2f(hp[j]) + bf2f(lp[j]);
        ++cnt;
      }
    }
    if (cur >= 0){
      #pragma unroll
      for (int j = 0; j < 8; ++j) unsafeAtomicAdd(&gsum[cur*256 + c*8 + j], a[j]);
      if (c == 0) unsafeAtomicAdd(&gcnt[cur], (float)cnt);
    }
  }
}

// ---------------- scorer MLP (pool-finalize + concat fused in) ----------------
__global__ void k_score(const float* __restrict__ gsum, const float* __restrict__ gcnt,
                        const float* __restrict__ hfin, const float* __restrict__ wm1,
                        const float* __restrict__ bm1, const float* __restrict__ wm2,
                        const float* __restrict__ bm2, float* __restrict__ out)
{
  __shared__ float cs[512];
  __shared__ float red[4];
  const int b = blockIdx.x, t = threadIdx.x;
  float inv = 1.0f / fmaxf(gcnt[b], 1.0f);
  cs[t]       = gsum[b*256 + t] * inv;
  cs[256 + t] = hfin[b*256 + t];
  __syncthreads();
  float v = 0.f;
  #pragma unroll 4
  for (int k = 0; k < 512; ++k) v = fmaf(cs[k], wm1[(long long)k*256 + t], v);
  v = fmaxf(v + bm1[t], 0.f) * wm2[t];
  #pragma unroll
  for (int off = 32; off > 0; off >>= 1) v += __shfl_down(v, off, 64);
  if ((t & 63) == 0) red[t >> 6] = v;
  __syncthreads();
  if (t == 0) out[b] = red[0] + red[1] + red[2] + red[3] + bm2[0];
}

} // namespace

extern "C" void kernel_launch(void* const* d_in, const int* in_sizes, int n_in,
                              void* d_out, int out_size, void* d_ws, size_t ws_size,
                              hipStream_t stream)
{
  const float* x     = (const float*)d_in[0];
  const int*   eidx  = (const int*)  d_in[1];
  const int*   batch = (const int*)  d_in[2];
  const int*   paths = (const int*)  d_in[3];
  const float* w1l   = (const float*)d_in[4];
  const float* b1l   = (const float*)d_in[5];
  const float* w1r   = (const float*)d_in[6];
  const float* w2l   = (const float*)d_in[7];
  const float* b2l   = (const float*)d_in[8];
  const float* w2r   = (const float*)d_in[9];
  const float* w_ih  = (const float*)d_in[10];
  const float* w_hh  = (const float*)d_in[11];
  const float* b_ih  = (const float*)d_in[12];
  const float* b_hh  = (const float*)d_in[13];
  const float* wm1   = (const float*)d_in[14];
  const float* bm1   = (const float*)d_in[15];
  const float* wm2   = (const float*)d_in[16];
  const float* bm2   = (const float*)d_in[17];

  const int* src = eidx;        // edge_index[0]
  const int* dst = eidx + NE;   // edge_index[1]

  // workspace layout (same footprint as the original session, ~138 MB)
  float* w    = (float*)d_ws;
  float* bufA = w;                         // region0: gather out hi/lo; later wT4 (1 MB)
  float* bufB = bufA + (long long)NN*ND;   // region1: h1 hi/lo -> node_emb hi/lo (in-place)
  float* xg   = bufB + (long long)NN*ND;   // 2048*1024 floats
  float* gsum = xg   + 2048*1024;          // 64*256
  float* gcnt = gsum + NB*ND;              // 64
  float* h0   = gcnt + 64;                 // 64*256 (final hidden state)
  float* c0   = h0   + NB*ND;              // 64*256 (unused; c lives in registers)
  float* h1   = c0   + NB*ND;              // 64*256 (unused)
  ushort* wt1H = (ushort*)(h1 + NB*ND);    // 256*512 each (bf16, fragment-swizzled)
  ushort* wt1L = wt1H + 256*512;
  ushort* wt2H = wt1L + 256*512;
  ushort* wt2L = wt2H + 256*512;
  ushort* fb16 = wt2L + 256*512;           // N*256 bf16: x RNE copy (gather-1 input)

  ushort* A1H = (ushort*)bufA;             // gather mean, hi
  ushort* A1L = A1H + (long long)NN*ND;    // gather mean, lo
  ushort* h1H = (ushort*)bufB;             // h1 RNE-hi (layer1 out) -> node_emb hi (layer2, in-place)
  ushort* h1L = h1H + (long long)NN*ND;    // h1 residual-lo       -> node_emb lo
  float4* wT4 = (float4*)bufA;             // 64*1024 float4 (1 MB); aliased: bufA dead after GEMM-2

  // CSR scratch aliased into xg region (dead until k_xgate runs, after layer 2)
  int* cnt    = (int*)xg;        // 50432
  int* offs   = cnt    + 50432;  // 50432
  int* cursor = offs   + 50432;  // 50432
  int* bsum   = cursor + 50432;  // 256
  int* bsum2  = bsum   + 256;    // 256
  int* csr    = bsum2  + 256;    // 800000

  // ---- weight prep (fragment-swizzled bf16 hi/lo split) ----
  k_wsplit<<<512, 256, 0, stream>>>(w1l, w1r, wt1H, wt1L);
  k_wsplit<<<512, 256, 0, stream>>>(w2l, w2r, wt2H, wt2L);

  // ---- x -> bf16 RNE copy (gather-1 input) ----
  k_tobf16<<<(NN*ND/8 + 255)/256, 256, 0, stream>>>(x, fb16);

  // ---- build CSR (counting sort by dst), shared by both layers ----
  hipMemsetAsync(cnt, 0, 50432*sizeof(int), stream);
  k_hist<<<1024, 256, 0, stream>>>(dst, cnt);
  k_scan_block<<<NSCAN, 256, 0, stream>>>(cnt, offs, bsum);
  k_scan_top<<<1, 256, 0, stream>>>(bsum, bsum2);
  k_scan_add<<<NSCAN, 256, 0, stream>>>(offs, bsum2, cursor);
  k_fill<<<1024, 256, 0, stream>>>(src, dst, cursor, csr);

  // ---- layer 1: gather-mean (pre-split); GEMM A2 = x fp32 (alias-free), relu ----
  k_gather_bf16<<<NN, 256, 0, stream>>>(fb16, offs, csr, A1H, A1L);
  k_gemm<1,1><<<782, 256, 0, stream>>>(A1H, A1L, nullptr, nullptr, x,
                                       wt1H, wt1L, b1l, h1H, h1L);

  // ---- layer 2: gather over RNE(relu(h1)) = h1H; GEMM all-pre-split, in-place ----
  k_gather_bf16<<<NN, 256, 0, stream>>>(h1H, offs, csr, A1H, A1L);
  k_gemm<0,0><<<782, 256, 0, stream>>>(A1H, A1L, h1H, h1L, nullptr,
                                       wt2H, wt2L, b2l, h1H, h1L);

  // ---- w_hh transpose+pack (bufA region now dead -> holds wT4) ----
  k_wtrans<<<64, 256, 0, stream>>>(w_hh, wT4);

  // ---- global mean pool (chunk-parallel, vectorized) ----
  hipMemsetAsync(gsum, 0, (NB*ND + 64)*sizeof(float), stream);
  k_pool<<<NPOOL, 256, 0, stream>>>(h1H, h1L, batch, gsum, gcnt);

  // ---- LSTM input gates (overwrites the CSR alias region — CSR dead by now) ----
  k_xgate<<<dim3((NB*NL)/64, 1024/256), 256, 0, stream>>>(h1H, h1L, paths, w_ih, b_ih, b_hh, xg);

  // ---- LSTM recurrence: ONE launch, one block per independent batch sequence ----
  k_lstm_batch<<<NB, 1024, 0, stream>>>(xg, wT4, h0);
  // h0 = final hidden state

  // ---- fused concat + scorer ----
  k_score<<<NB, 256, 0, stream>>>(gsum, gcnt, h0, wm1, bm1, wm2, bm2, (float*)d_out);
}